// Round 5
// baseline (223.419 us; speedup 1.0000x reference)
//
#include <hip/hip_runtime.h>

// ConvSoftArgmax2d: x (8,16,512,512) fp32 -> coords (128,2,256,256), resp (128,1,256,256)
// 3x3 window, stride 2, pad 1. Padding contributes 0 to the pooled exp-sums.
// Each thread computes a 2x4 output tile (ho0=2hp, ho1=2hp+1; wo=4t..4t+3):
// the 2 output rows share input row 4hp+1 -> 5 input rows x 9 cols = 15 VMEM loads,
// all independent and issued up-front for MLP. Nontemporal stores keep L2/L3 clean.

#define H  512
#define W  512
#define HO 256
#define WO 256
#define BC 128

typedef float f32x4 __attribute__((ext_vector_type(4)));  // native vector: valid for nontemporal builtin

struct Acc { float den, numv, gx, gy; };

__device__ __forceinline__ void accum_row(const float* __restrict__ v,
                                          const float* __restrict__ e,
                                          float rs, Acc* __restrict__ a)
{
#pragma unroll
    for (int j = 0; j < 4; ++j) {
        float e0 = e[2 * j], e1 = e[2 * j + 1], e2 = e[2 * j + 2];
        float rsum = e0 + e1 + e2;
        a[j].den += rsum;
        a[j].gy   = fmaf(rs, rsum, a[j].gy);
        a[j].gx  += e2 - e0;
        a[j].numv = fmaf(e0, v[2 * j],
                    fmaf(e1, v[2 * j + 1],
                    fmaf(e2, v[2 * j + 2], a[j].numv)));
    }
}

__global__ __launch_bounds__(256) void casm_kernel(
    const float* __restrict__ x, const float* __restrict__ temp,
    float* __restrict__ out)
{
    int idx = blockIdx.x * 256 + threadIdx.x;
    int t  = idx & 63;                 // wo quad: wo = 4t+j
    int hp = (idx >> 6) & 127;         // ho pair: ho0 = 2hp, ho1 = 2hp+1 (wave-uniform)
    int bc = idx >> 13;

    float k  = 1.44269504088896340736f / fmaxf(temp[0], 1e-8f);
    float mL = t ? 1.0f : 0.0f;        // left-column mask (t==0)

    const float* __restrict__ xp = x + (size_t)bc * (H * W);
    int r0 = 4 * hp - 1;               // top row; <0 only when hp==0 (wave-uniform)
    float m0 = (r0 >= 0) ? 1.0f : 0.0f;

    // ---- load all 5 rows x 9 cols (15 independent VMEM ops) ----
    float v[5][9];
#pragma unroll
    for (int rr = 0; rr < 5; ++rr) {
        int r = r0 + rr;
        const float* __restrict__ row = xp + (r < 0 ? 0 : r) * W;
        v[rr][0] = row[t ? 8 * t - 1 : 0];              // col 8t-1 (clamped for t=0)
        f32x4 q1 = *(const f32x4*)(row + 8 * t);        // cols 8t..8t+3
        f32x4 q2 = *(const f32x4*)(row + 8 * t + 4);    // cols 8t+4..8t+7
        v[rr][1] = q1.x; v[rr][2] = q1.y; v[rr][3] = q1.z; v[rr][4] = q1.w;
        v[rr][5] = q2.x; v[rr][6] = q2.y; v[rr][7] = q2.z; v[rr][8] = q2.w;
    }

    Acc A[4], B[4];
#pragma unroll
    for (int j = 0; j < 4; ++j) {
        A[j].den = 1e-12f; A[j].numv = 0.f; A[j].gx = 0.f; A[j].gy = 0.f;
        B[j].den = 1e-12f; B[j].numv = 0.f; B[j].gx = 0.f; B[j].gy = 0.f;
    }

    float e[9];
    // row 0 -> A (rs=-1), masked by m0 (hp==0 padding)
#pragma unroll
    for (int i = 0; i < 9; ++i) e[i] = m0 * __builtin_amdgcn_exp2f(k * v[0][i]);
    e[0] *= mL;
    accum_row(v[0], e, -1.0f, A);
    // row 1 -> A (rs=0)
#pragma unroll
    for (int i = 0; i < 9; ++i) e[i] = __builtin_amdgcn_exp2f(k * v[1][i]);
    e[0] *= mL;
    accum_row(v[1], e, 0.0f, A);
    // row 2 -> A (rs=+1) and B (rs=-1), shared
#pragma unroll
    for (int i = 0; i < 9; ++i) e[i] = __builtin_amdgcn_exp2f(k * v[2][i]);
    e[0] *= mL;
    accum_row(v[2], e,  1.0f, A);
    accum_row(v[2], e, -1.0f, B);
    // row 3 -> B (rs=0)
#pragma unroll
    for (int i = 0; i < 9; ++i) e[i] = __builtin_amdgcn_exp2f(k * v[3][i]);
    e[0] *= mL;
    accum_row(v[3], e, 0.0f, B);
    // row 4 -> B (rs=+1)
#pragma unroll
    for (int i = 0; i < 9; ++i) e[i] = __builtin_amdgcn_exp2f(k * v[4][i]);
    e[0] *= mL;
    accum_row(v[4], e, 1.0f, B);

    // ---- epilogue: 2 output rows x 4 outputs ----
    const float scale = 2.0f / 511.0f;
    size_t cstride = (size_t)HO * WO;
    size_t obase   = (size_t)bc * (2 * cstride);
    size_t rbase   = (size_t)BC * 2 * cstride + (size_t)bc * cstride;

#pragma unroll
    for (int rr = 0; rr < 2; ++rr) {
        Acc* a = rr ? B : A;
        int ho = 2 * hp + rr;
        f32x4 cx4, cy4, rp4;
#pragma unroll
        for (int j = 0; j < 4; ++j) {
            float inv_den = __builtin_amdgcn_rcpf(a[j].den);
            int wo = 4 * t + j;
            cx4[j] = (a[j].gx * inv_den + (float)(2 * wo)) * scale - 1.0f;
            cy4[j] = (a[j].gy * inv_den + (float)(2 * ho)) * scale - 1.0f;
            rp4[j] = a[j].numv * inv_den;
        }
        size_t pix = (size_t)ho * WO + 4 * t;           // 16B aligned
        __builtin_nontemporal_store(cx4, (f32x4*)(out + obase + pix));
        __builtin_nontemporal_store(cy4, (f32x4*)(out + obase + cstride + pix));
        __builtin_nontemporal_store(rp4, (f32x4*)(out + rbase + pix));
    }
}

extern "C" void kernel_launch(void* const* d_in, const int* in_sizes, int n_in,
                              void* d_out, int out_size, void* d_ws, size_t ws_size,
                              hipStream_t stream) {
    const float* x    = (const float*)d_in[0];
    const float* temp = (const float*)d_in[1];
    float* out        = (float*)d_out;

    int total  = BC * (HO / 2) * (WO / 4);  // 1,048,576 threads (8 outputs each)
    int blocks = total / 256;               // 4096
    casm_kernel<<<blocks, 256, 0, stream>>>(x, temp, out);
}

// Round 6
// 221.686 us; speedup vs baseline: 1.0078x; 1.0078x over previous
//
#include <hip/hip_runtime.h>

// ConvSoftArgmax2d: x (8,16,512,512) fp32 -> coords (128,2,256,256), resp (128,1,256,256)
// 3x3 window, stride 2, pad 1.
// LDS-staged: block = 4 output rows x 256 wo (one bc). Staging loads 9 input rows
// x 512 cols with per-lane-contiguous 32B loads (coalesced, full-line coverage),
// deinterleaved into even/odd column arrays in LDS so the stride-2 window reads
// become aligned ds_read_b128. Padding cells hold -1e4 (exp2 underflows to 0).

#define H  512
#define W  512
#define HO 256
#define WO 256
#define BC 128

typedef float f32x4 __attribute__((ext_vector_type(4)));

// LDS row layout (words): [0..255] even cols (even[i] = x[2i]),
// [259] odd[-1] pad, [260..515] odd (odd[i] = x[2i+1]). Stride 520.
#define ROWSTRIDE 520

__global__ __launch_bounds__(256) void casm_kernel(
    const float* __restrict__ x, const float* __restrict__ temp,
    float* __restrict__ out)
{
    __shared__ float lds[9 * ROWSTRIDE];   // 18.7 KB

    int tid = threadIdx.x;
    int hq  = blockIdx.x & 63;            // output row group: ho = 4hq..4hq+3
    int bc  = blockIdx.x >> 6;

    float k = 1.44269504088896340736f / fmaxf(temp[0], 1e-8f);

    const float* __restrict__ xp = x + (size_t)bc * (H * W);
    int r0 = 8 * hq - 1;                  // top input row; -1 only for hq==0

    // ---- staging: 9 rows x 512 cols = 576 chunks of 8 floats ----
#pragma unroll
    for (int p = 0; p < 3; ++p) {
        int chunk = tid + p * 256;
        if (chunk < 576) {
            int rr = chunk >> 6, c8 = chunk & 63;
            int r = r0 + rr;
            f32x4 q1, q2;
            if (r >= 0) {                                  // wave-uniform
                const float* row = xp + r * W + 8 * c8;
                q1 = *(const f32x4*)row;
                q2 = *(const f32x4*)(row + 4);
            } else {
                q1 = q2 = (f32x4)(-1e4f);                  // top pad row
            }
            f32x4 ev = {q1.x, q1.z, q2.x, q2.z};           // cols 8c8, 8c8+2, +4, +6
            f32x4 od = {q1.y, q1.w, q2.y, q2.w};           // cols 8c8+1, +3, +5, +7
            *(f32x4*)&lds[rr * ROWSTRIDE + 4 * c8]       = ev;
            *(f32x4*)&lds[rr * ROWSTRIDE + 260 + 4 * c8] = od;
        }
    }
    if (tid < 9) lds[tid * ROWSTRIDE + 259] = -1e4f;       // odd[-1] = left pad
    __syncthreads();

    // ---- compute: thread = (oh = tid>>6, t = tid&63), outputs wo = 4t..4t+3 ----
    int t  = tid & 63;
    int oh = tid >> 6;                     // wave-uniform
    int ho = 4 * hq + oh;

    float den[4] = {1e-12f, 1e-12f, 1e-12f, 1e-12f};
    float numv[4] = {0.f, 0.f, 0.f, 0.f};
    float gx[4] = {0.f, 0.f, 0.f, 0.f};
    float gy[4] = {0.f, 0.f, 0.f, 0.f};

#pragma unroll
    for (int dr = 0; dr < 3; ++dr) {       // window rows: local rows 2oh+dr
        int rbase = (2 * oh + dr) * ROWSTRIDE;
        float rs = (float)(dr - 1);
        f32x4 ev = *(const f32x4*)&lds[rbase + 4 * t];          // even[4t..4t+3]
        f32x4 od = *(const f32x4*)&lds[rbase + 260 + 4 * t];    // odd[4t..4t+3]
        float om = lds[rbase + 259 + 4 * t];                    // odd[4t-1]

        float em = __builtin_amdgcn_exp2f(k * om);
        f32x4 ee, eo;
#pragma unroll
        for (int j = 0; j < 4; ++j) {
            ee[j] = __builtin_amdgcn_exp2f(k * ev[j]);
            eo[j] = __builtin_amdgcn_exp2f(k * od[j]);
        }
#pragma unroll
        for (int j = 0; j < 4; ++j) {
            float e0 = j ? eo[j - 1] : em;   // col 2wo-1
            float v0 = j ? od[j - 1] : om;
            float e1 = ee[j], v1 = ev[j];    // col 2wo
            float e2 = eo[j], v2 = od[j];    // col 2wo+1
            float rsum = e0 + e1 + e2;
            den[j] += rsum;
            gy[j]   = fmaf(rs, rsum, gy[j]);
            gx[j]  += e2 - e0;
            numv[j] = fmaf(e0, v0, fmaf(e1, v1, fmaf(e2, v2, numv[j])));
        }
    }

    // ---- epilogue ----
    const float scale = 2.0f / 511.0f;
    f32x4 cx4, cy4, rp4;
#pragma unroll
    for (int j = 0; j < 4; ++j) {
        float inv_den = __builtin_amdgcn_rcpf(den[j]);
        int wo = 4 * t + j;
        cx4[j] = (gx[j] * inv_den + (float)(2 * wo)) * scale - 1.0f;
        cy4[j] = (gy[j] * inv_den + (float)(2 * ho)) * scale - 1.0f;
        rp4[j] = numv[j] * inv_den;
    }

    size_t cstride = (size_t)HO * WO;
    size_t pix     = (size_t)ho * WO + 4 * t;                  // 16B aligned
    size_t cbase   = (size_t)bc * (2 * cstride) + pix;
    *(f32x4*)(out + cbase)           = cx4;                    // channel 0: x
    *(f32x4*)(out + cbase + cstride) = cy4;                    // channel 1: y
    *(f32x4*)(out + (size_t)BC * 2 * cstride + (size_t)bc * cstride + pix) = rp4;
}

extern "C" void kernel_launch(void* const* d_in, const int* in_sizes, int n_in,
                              void* d_out, int out_size, void* d_ws, size_t ws_size,
                              hipStream_t stream) {
    const float* x    = (const float*)d_in[0];
    const float* temp = (const float*)d_in[1];
    float* out        = (float*)d_out;

    int blocks = BC * (HO / 4);            // 8192 blocks x 256 threads
    casm_kernel<<<blocks, 256, 0, stream>>>(x, temp, out);
}